// Round 6
// baseline (467.060 us; speedup 1.0000x reference)
//
#include <hip/hip_runtime.h>

// ---------------------------------------------------------------------------
// GQA forward, fp32 I/O, bf16 MFMA compute.
// B=2 S=2048 D=2048 HQ=32 HKV=8 HD=64.
// 6 kernels: cvt4(x,Wq,Wk,Wv) -> QKV GEMM w/ fused RoPE epilogue (q scaled by
// 0.125*log2e) + XCD supertile swizzle -> V transpose -> flash attn (PAIRED
// q-blocks, dbuf, exp2, ones-MFMA l-sum, RS=68) -> cvt(Wo) -> O GEMM.
// ---------------------------------------------------------------------------

typedef __bf16 bf16x8 __attribute__((ext_vector_type(8)));
typedef __bf16 bf16x4 __attribute__((ext_vector_type(4)));
typedef float f32x4 __attribute__((ext_vector_type(4)));

__device__ inline f32x4 mfma16(bf16x8 a, bf16x8 b, f32x4 c) {
    return __builtin_amdgcn_mfma_f32_16x16x32_bf16(a, b, c, 0, 0, 0);
}

__device__ inline void gld16(const __bf16* g, __bf16* l) {
    __builtin_amdgcn_global_load_lds(
        (const __attribute__((address_space(1))) void*)g,
        (__attribute__((address_space(3))) void*)l, 16, 0, 0);
}

__device__ inline bf16x4 pk4(float a, float b, float c, float d) {
    bf16x4 r; r[0] = (__bf16)a; r[1] = (__bf16)b; r[2] = (__bf16)c; r[3] = (__bf16)d;
    return r;
}

#define SCALE_Q 0.18033688011112042f   // (1/8) * log2(e)
#define L2IF    0.4152410118609203f    // log2(10000)/32
#define INV2PI  0.15915494309189535f

// ---------------- fused fp32->bf16 for x, Wq, Wk, Wv ------------------------
__global__ void cvt4_kernel(const float* __restrict__ x,  const float* __restrict__ wq,
                            const float* __restrict__ wk, const float* __restrict__ wv,
                            __bf16* __restrict__ xb, __bf16* __restrict__ wqkvb)
{
    int i = blockIdx.x * blockDim.x + threadIdx.x;
    const float* src; __bf16* dst;
    if (i < 2097152)      { src = x  + (size_t)i * 4;  dst = xb + (size_t)i * 4; }
    else if (i < 3145728) { int j = i - 2097152; src = wq + (size_t)j * 4; dst = wqkvb + (size_t)j * 4; }
    else if (i < 3407872) { int j = i - 3145728; src = wk + (size_t)j * 4; dst = wqkvb + 4194304 + (size_t)j * 4; }
    else                  { int j = i - 3407872; src = wv + (size_t)j * 4; dst = wqkvb + 5242880 + (size_t)j * 4; }
    float4 f = *(const float4*)src;
    *(bf16x4*)dst = pk4(f.x, f.y, f.z, f.w);
}

__global__ void cvt_kernel(const float* __restrict__ in, __bf16* __restrict__ out, int n4)
{
    int i = blockIdx.x * blockDim.x + threadIdx.x;
    if (i >= n4) return;
    float4 f = ((const float4*)in)[i];
    ((bf16x4*)out)[i] = pk4(f.x, f.y, f.z, f.w);
}

// ---------------- GEMM: C[M,N] = A[M,K] * Bw[N,K]^T (bf16, fp32 acc) -------
// m97 structure + XCD supertile swizzle (requires gridDim.y == 32).
#define BK 32

template<bool ROPE, bool OUT_F32>
__global__ __launch_bounds__(256) void gemm_bt(
    const __bf16* __restrict__ A, const __bf16* __restrict__ Bw,
    void* __restrict__ Cv, int M, int N, int K)
{
    __shared__ __bf16 As[128 * BK];
    __shared__ __bf16 Bs[128 * BK];
    const int tid  = threadIdx.x;
    const int lane = tid & 63;
    const int w    = tid >> 6;
    const int lm   = lane & 15;
    const int quad = lane >> 4;
    const int wm   = (w >> 1) * 64;
    const int wn   = (w & 1) * 64;

    // XCD-aware supertile swizzle: dispatch id -> XCD is round-robin (id%8).
    // Each XCD owns a 4-row M-band and sweeps N with M-minor 4: B tiles are
    // fetched ~once per XCD, the A band stays resident in its private L2.
    int bx, by;
    {
        int id  = blockIdx.x + gridDim.x * blockIdx.y;
        int xcd = id & 7;
        int j   = id >> 3;
        by = xcd * 4 + (j & 3);      // gy == 32
        bx = j >> 2;
    }
    const int m0 = by * 128;
    const int n0 = bx * 128;

    f32x4 acc[4][4];
    #pragma unroll
    for (int i = 0; i < 4; ++i)
        #pragma unroll
        for (int j = 0; j < 4; ++j)
            acc[i][j] = (f32x4){0.f, 0.f, 0.f, 0.f};

    const int srow = tid >> 2;
    const int sc8  = (tid & 3) * 8;
    const __bf16* gA0 = A  + (size_t)(m0 + srow) * K + sc8;
    const __bf16* gA1 = gA0 + (size_t)64 * K;
    const __bf16* gB0 = Bw + (size_t)(n0 + srow) * K + sc8;
    const __bf16* gB1 = gB0 + (size_t)64 * K;
    __bf16* lA0 = &As[srow * BK + sc8];
    __bf16* lA1 = &As[(srow + 64) * BK + sc8];
    __bf16* lB0 = &Bs[srow * BK + sc8];
    __bf16* lB1 = &Bs[(srow + 64) * BK + sc8];

    for (int k0 = 0; k0 < K; k0 += BK) {
        gld16(gA0 + k0, lA0);
        gld16(gA1 + k0, lA1);
        gld16(gB0 + k0, lB0);
        gld16(gB1 + k0, lB1);
        __syncthreads();

        bf16x8 af[4], bfr[4];
        #pragma unroll
        for (int i = 0; i < 4; ++i)
            af[i] = *(const bf16x8*)&As[(wm + i * 16 + lm) * BK + quad * 8];
        #pragma unroll
        for (int j = 0; j < 4; ++j)
            bfr[j] = *(const bf16x8*)&Bs[(wn + j * 16 + lm) * BK + quad * 8];
        #pragma unroll
        for (int i = 0; i < 4; ++i)
            #pragma unroll
            for (int j = 0; j < 4; ++j)
                acc[i][j] = mfma16(af[i], bfr[j], acc[i][j]);
        __syncthreads();
    }

    float sc = 1.0f;
    if (ROPE) {
        const int colbase = n0 + wn;            // 64-aligned; region-uniform per wave
        const int region  = (colbase < 2048) ? 0 : (colbase < 2560 ? 1 : 2);
        if (region < 2) {
            if (region == 0) sc = SCALE_Q;
            float invr[2];
            invr[0] = exp2f(-(float)lm        * L2IF) * INV2PI;
            invr[1] = exp2f(-(float)(16 + lm) * L2IF) * INV2PI;
            #pragma unroll
            for (int i = 0; i < 4; ++i)
                #pragma unroll
                for (int r = 0; r < 4; ++r) {
                    float t = (float)((m0 + wm + i * 16 + quad * 4 + r) & 2047);
                    #pragma unroll
                    for (int jp = 0; jp < 2; ++jp) {
                        float a = t * invr[jp];
                        a -= floorf(a);                       // revolutions in [0,1)
                        float cs = __builtin_amdgcn_cosf(a);
                        float sn = __builtin_amdgcn_sinf(a);
                        float x1 = acc[i][jp][r], x2 = acc[i][jp + 2][r];
                        acc[i][jp][r]     = x1 * cs - x2 * sn;
                        acc[i][jp + 2][r] = x2 * cs + x1 * sn;
                    }
                }
        }
    }

    #pragma unroll
    for (int i = 0; i < 4; ++i)
        #pragma unroll
        for (int j = 0; j < 4; ++j)
            #pragma unroll
            for (int r = 0; r < 4; ++r) {
                int row = m0 + wm + i * 16 + quad * 4 + r;
                int col = n0 + wn + j * 16 + lm;
                if (OUT_F32)
                    ((float*)Cv)[(size_t)row * N + col] = acc[i][j][r];
                else
                    ((__bf16*)Cv)[(size_t)row * N + col] = (__bf16)(acc[i][j][r] * sc);
            }
}

// ---------------- V transpose: [4096 tok][512 d] (stride 3072) -> [512][4096]
__global__ __launch_bounds__(256) void transpose_kernel(
    const __bf16* __restrict__ in, __bf16* __restrict__ out, int rowstride)
{
    __shared__ __bf16 T[64][72];
    const int t0 = blockIdx.x * 64;
    const int d0 = blockIdx.y * 64;
    const int r = threadIdx.x >> 2, c = (threadIdx.x & 3) * 16;
    *(int4*)&T[r][c]     = *(const int4*)(in + (size_t)(t0 + r) * rowstride + d0 + c);
    *(int4*)&T[r][c + 8] = *(const int4*)(in + (size_t)(t0 + r) * rowstride + d0 + c + 8);
    __syncthreads();
    bf16x8 o0, o1;
    #pragma unroll
    for (int i = 0; i < 8; ++i) { o0[i] = T[c + i][r]; o1[i] = T[c + 8 + i][r]; }
    *(bf16x8*)(out + (size_t)(d0 + r) * 4096 + t0 + c)     = o0;
    *(bf16x8*)(out + (size_t)(d0 + r) * 4096 + t0 + c + 8) = o1;
}

// ---------------- Flash attention ------------------------------------------
// Paired q-blocks (p, 15-p): uniform 34 tile-works/block, real ILP between
// the two works inside one barrier period. St = mfma(A=K, B=Q); p = exp2(St)
// (q pre-scaled by 0.125*log2e); l via ones-MFMA; PV = mfma(A=Vt, B=Pt).
#define RS  68
#define PKS 68

__device__ inline void attn_tile(
    const bf16x8 (&qf)[2][2], f32x4 (&oacc)[2][4], f32x4 (&lacc)[2],
    const bf16x8& vone, int qbase, int k0, int w, int lm, int quad,
    const __bf16* Ks, const __bf16* Vs, __bf16* Ptw)
{
    f32x4 st[2][4];
    #pragma unroll
    for (int m = 0; m < 2; ++m)
        #pragma unroll
        for (int n = 0; n < 4; ++n)
            st[m][n] = (f32x4){0.f, 0.f, 0.f, 0.f};

    #pragma unroll
    for (int n = 0; n < 4; ++n) {
        bf16x8 kf0 = *(const bf16x8*)&Ks[(n * 16 + lm) * RS + quad * 8];
        bf16x8 kf1 = *(const bf16x8*)&Ks[(n * 16 + lm) * RS + 32 + quad * 8];
        #pragma unroll
        for (int m = 0; m < 2; ++m) {
            st[m][n] = mfma16(kf0, qf[m][0], st[m][n]);
            st[m][n] = mfma16(kf1, qf[m][1], st[m][n]);
        }
    }

    const bool any_mask = (k0 + 63 > qbase + w * 32);
    #pragma unroll
    for (int m = 0; m < 2; ++m) {
        const int qi = qbase + w * 32 + m * 16 + lm;
        #pragma unroll
        for (int n = 0; n < 4; ++n) {
            const int kv0 = k0 + n * 16 + quad * 4;
            float e0, e1, e2, e3;
            if (any_mask) {
                e0 = (kv0     > qi) ? 0.f : exp2f(st[m][n][0]);
                e1 = (kv0 + 1 > qi) ? 0.f : exp2f(st[m][n][1]);
                e2 = (kv0 + 2 > qi) ? 0.f : exp2f(st[m][n][2]);
                e3 = (kv0 + 3 > qi) ? 0.f : exp2f(st[m][n][3]);
            } else {
                e0 = exp2f(st[m][n][0]); e1 = exp2f(st[m][n][1]);
                e2 = exp2f(st[m][n][2]); e3 = exp2f(st[m][n][3]);
            }
            *(bf16x4*)&Ptw[(m * 16 + lm) * PKS + n * 16 + quad * 4] = pk4(e0, e1, e2, e3);
        }
    }

    bf16x8 pf[2][2];
    #pragma unroll
    for (int m = 0; m < 2; ++m) {
        pf[m][0] = *(const bf16x8*)&Ptw[(m * 16 + lm) * PKS + quad * 8];
        pf[m][1] = *(const bf16x8*)&Ptw[(m * 16 + lm) * PKS + 32 + quad * 8];
    }
    #pragma unroll
    for (int m = 0; m < 2; ++m) {
        lacc[m] = mfma16(vone, pf[m][0], lacc[m]);
        lacc[m] = mfma16(vone, pf[m][1], lacc[m]);
    }
    #pragma unroll
    for (int dt = 0; dt < 4; ++dt) {
        bf16x8 vf0 = *(const bf16x8*)&Vs[(dt * 16 + lm) * RS + quad * 8];
        bf16x8 vf1 = *(const bf16x8*)&Vs[(dt * 16 + lm) * RS + 32 + quad * 8];
        #pragma unroll
        for (int m = 0; m < 2; ++m) {
            oacc[m][dt] = mfma16(vf0, pf[m][0], oacc[m][dt]);
            oacc[m][dt] = mfma16(vf1, pf[m][1], oacc[m][dt]);
        }
    }
}

__device__ inline void attn_epilogue(
    f32x4 (&oacc)[2][4], f32x4 (&lacc)[2],
    int qbase, int w, int lm, int quad, int b, int h, __bf16* o)
{
    #pragma unroll
    for (int m = 0; m < 2; ++m) {
        float rinv = 1.0f / lacc[m][0];
        const size_t rowbase = (size_t)(b * 2048 + qbase + w * 32 + m * 16 + lm) * 2048 + h * 64;
        #pragma unroll
        for (int dt = 0; dt < 4; ++dt)
            *(bf16x4*)(o + rowbase + dt * 16 + quad * 4) =
                pk4(oacc[m][dt][0] * rinv, oacc[m][dt][1] * rinv,
                    oacc[m][dt][2] * rinv, oacc[m][dt][3] * rinv);
    }
}

__global__ __launch_bounds__(256) void attn_kernel(
    const __bf16* __restrict__ qkv, const __bf16* __restrict__ vt,
    __bf16* __restrict__ o)
{
    __shared__ __bf16 Ks[2][64 * RS];
    __shared__ __bf16 Vs[2][64 * RS];
    __shared__ __bf16 Pt[4][32 * PKS];
    const int tid  = threadIdx.x;
    const int w    = tid >> 6;
    const int lane = tid & 63;
    const int lm   = lane & 15;
    const int quad = lane >> 4;
    const int p = blockIdx.x, h = blockIdx.y, b = blockIdx.z;
    const int kvh = h >> 2;
    const int qbA = p * 128, qbB = (15 - p) * 128;
    const int ntA = 2 * p + 2, ntB = 32 - 2 * p;
    __bf16* Ptw = &Pt[w][0];

    bf16x8 qfA[2][2], qfB[2][2];
    #pragma unroll
    for (int m = 0; m < 2; ++m)
        #pragma unroll
        for (int kh = 0; kh < 2; ++kh) {
            qfA[m][kh] = *(const bf16x8*)(qkv + (size_t)(b * 2048 + qbA + w * 32 + m * 16 + lm) * 3072
                                            + h * 64 + kh * 32 + quad * 8);
            qfB[m][kh] = *(const bf16x8*)(qkv + (size_t)(b * 2048 + qbB + w * 32 + m * 16 + lm) * 3072
                                            + h * 64 + kh * 32 + quad * 8);
        }

    bf16x8 vone;
    #pragma unroll
    for (int i = 0; i < 8; ++i) vone[i] = (__bf16)1.0f;

    f32x4 oA[2][4], oB[2][4], lA[2], lB[2];
    #pragma unroll
    for (int m = 0; m < 2; ++m) {
        lA[m] = (f32x4){0.f, 0.f, 0.f, 0.f};
        lB[m] = (f32x4){0.f, 0.f, 0.f, 0.f};
        #pragma unroll
        for (int j = 0; j < 4; ++j) {
            oA[m][j] = (f32x4){0.f, 0.f, 0.f, 0.f};
            oB[m][j] = (f32x4){0.f, 0.f, 0.f, 0.f};
        }
    }

    const int srow = tid >> 2;
    const int scol = (tid & 3) * 16;
    const __bf16* kbase = qkv + (size_t)(b * 2048) * 3072 + 2048 + kvh * 64;
    const __bf16* vbase = vt  + (size_t)(kvh * 64 + srow) * 4096 + b * 2048;

    int4 kr0, kr1, vr0, vr1;
    {
        const __bf16* kr = kbase + (size_t)srow * 3072 + scol;
        kr0 = *(const int4*)kr; kr1 = *(const int4*)(kr + 8);
        vr0 = *(const int4*)(vbase + scol); vr1 = *(const int4*)(vbase + scol + 8);
    }

    for (int kt = 0; kt < ntB; ++kt) {
        const int c = kt & 1;
        const int k0 = kt * 64;
        *(int4*)&Ks[c][srow * RS + scol]     = kr0;
        *(int4*)&Ks[c][srow * RS + scol + 8] = kr1;
        *(int4*)&Vs[c][srow * RS + scol]     = vr0;
        *(int4*)&Vs[c][srow * RS + scol + 8] = vr1;
        if (kt + 1 < ntB) {
            const __bf16* kr = kbase + (size_t)(k0 + 64 + srow) * 3072 + scol;
            kr0 = *(const int4*)kr; kr1 = *(const int4*)(kr + 8);
            vr0 = *(const int4*)(vbase + k0 + 64 + scol);
            vr1 = *(const int4*)(vbase + k0 + 64 + scol + 8);
        }
        __syncthreads();
        attn_tile(qfB, oB, lB, vone, qbB, k0, w, lm, quad, Ks[c], Vs[c], Ptw);
        if (kt < ntA)
            attn_tile(qfA, oA, lA, vone, qbA, k0, w, lm, quad, Ks[c], Vs[c], Ptw);
    }

    attn_epilogue(oA, lA, qbA, w, lm, quad, b, h, o);
    attn_epilogue(oB, lB, qbB, w, lm, quad, b, h, o);
}

// ---------------------------------------------------------------------------
extern "C" void kernel_launch(void* const* d_in, const int* in_sizes, int n_in,
                              void* d_out, int out_size, void* d_ws, size_t ws_size,
                              hipStream_t stream)
{
    const float* x  = (const float*)d_in[0];
    const float* Wq = (const float*)d_in[1];
    const float* Wk = (const float*)d_in[2];
    const float* Wv = (const float*)d_in[3];
    const float* Wo = (const float*)d_in[4];

    const size_t Mi = 1u << 20;
    // d_out (32 MiB fp32) is scratch until the final GEMM writes it.
    char* ob = (char*)d_out;
    __bf16* xb    = (__bf16*)ob;              // 16 MiB  [4096][2048]
    __bf16* wqkvb = (__bf16*)(ob + 16 * Mi);  // 12 MiB  [3072][2048]
    __bf16* vt    = (__bf16*)(ob + 28 * Mi);  //  4 MiB  [512][4096]
    // d_ws (>= 40 MiB, proven)
    char* ws = (char*)d_ws;
    __bf16* qkvc = (__bf16*)ws;               // 24 MiB  [4096][3072]  Q|K|V
    __bf16* aws  = (__bf16*)(ws + 24 * Mi);   // 16 MiB  [4096][2048]
    __bf16* wob  = (__bf16*)ws;               //  8 MiB, reuses qkvc after attn

    dim3 blk(256);
    cvt4_kernel<<<14336, blk, 0, stream>>>(x, Wq, Wk, Wv, xb, wqkvb);
    gemm_bt<true, false><<<dim3(24, 32), blk, 0, stream>>>(xb, wqkvb, qkvc, 4096, 3072, 2048);
    transpose_kernel<<<dim3(64, 8), blk, 0, stream>>>(qkvc + 2560, vt, 3072);
    attn_kernel<<<dim3(8, 32, 2), blk, 0, stream>>>(qkvc, vt, aws);
    cvt_kernel<<<4096, blk, 0, stream>>>(Wo, wob, 1048576);
    gemm_bt<false, true><<<dim3(16, 32), blk, 0, stream>>>(aws, wob, d_out, 4096, 2048, 2048);
}

// Round 7
// 346.699 us; speedup vs baseline: 1.3472x; 1.3472x over previous
//
#include <hip/hip_runtime.h>

// ---------------------------------------------------------------------------
// GQA forward, fp32 I/O, bf16 MFMA compute.
// B=2 S=2048 D=2048 HQ=32 HKV=8 HD=64.
// 6 kernels: cvt4(x,Wq,Wk,Wv) -> QKV GEMM w/ fused RoPE epilogue (q scaled by
// 0.125) + XCD supertile swizzle -> V transpose -> flash attn (ROUND-4 exact:
// paired q-blocks, RS=72, __expf, scalar l, dbuf) -> cvt(Wo) -> O GEMM.
// ---------------------------------------------------------------------------

typedef __bf16 bf16x8 __attribute__((ext_vector_type(8)));
typedef __bf16 bf16x4 __attribute__((ext_vector_type(4)));
typedef float f32x4 __attribute__((ext_vector_type(4)));

__device__ inline f32x4 mfma16(bf16x8 a, bf16x8 b, f32x4 c) {
    return __builtin_amdgcn_mfma_f32_16x16x32_bf16(a, b, c, 0, 0, 0);
}

__device__ inline void gld16(const __bf16* g, __bf16* l) {
    __builtin_amdgcn_global_load_lds(
        (const __attribute__((address_space(1))) void*)g,
        (__attribute__((address_space(3))) void*)l, 16, 0, 0);
}

__device__ inline bf16x4 pk4(float a, float b, float c, float d) {
    bf16x4 r; r[0] = (__bf16)a; r[1] = (__bf16)b; r[2] = (__bf16)c; r[3] = (__bf16)d;
    return r;
}

#define SCALE_Q 0.125f                 // 1/sqrt(64); attn uses native __expf
#define L2IF    0.4152410118609203f    // log2(10000)/32
#define INV2PI  0.15915494309189535f

// ---------------- fused fp32->bf16 for x, Wq, Wk, Wv ------------------------
__global__ void cvt4_kernel(const float* __restrict__ x,  const float* __restrict__ wq,
                            const float* __restrict__ wk, const float* __restrict__ wv,
                            __bf16* __restrict__ xb, __bf16* __restrict__ wqkvb)
{
    int i = blockIdx.x * blockDim.x + threadIdx.x;
    const float* src; __bf16* dst;
    if (i < 2097152)      { src = x  + (size_t)i * 4;  dst = xb + (size_t)i * 4; }
    else if (i < 3145728) { int j = i - 2097152; src = wq + (size_t)j * 4; dst = wqkvb + (size_t)j * 4; }
    else if (i < 3407872) { int j = i - 3145728; src = wk + (size_t)j * 4; dst = wqkvb + 4194304 + (size_t)j * 4; }
    else                  { int j = i - 3407872; src = wv + (size_t)j * 4; dst = wqkvb + 5242880 + (size_t)j * 4; }
    float4 f = *(const float4*)src;
    *(bf16x4*)dst = pk4(f.x, f.y, f.z, f.w);
}

__global__ void cvt_kernel(const float* __restrict__ in, __bf16* __restrict__ out, int n4)
{
    int i = blockIdx.x * blockDim.x + threadIdx.x;
    if (i >= n4) return;
    float4 f = ((const float4*)in)[i];
    ((bf16x4*)out)[i] = pk4(f.x, f.y, f.z, f.w);
}

// ---------------- GEMM: C[M,N] = A[M,K] * Bw[N,K]^T (bf16, fp32 acc) -------
// m97 structure + XCD supertile swizzle (requires gridDim.y == 32).
#define BK 32

template<bool ROPE, bool OUT_F32>
__global__ __launch_bounds__(256) void gemm_bt(
    const __bf16* __restrict__ A, const __bf16* __restrict__ Bw,
    void* __restrict__ Cv, int M, int N, int K)
{
    __shared__ __bf16 As[128 * BK];
    __shared__ __bf16 Bs[128 * BK];
    const int tid  = threadIdx.x;
    const int lane = tid & 63;
    const int w    = tid >> 6;
    const int lm   = lane & 15;
    const int quad = lane >> 4;
    const int wm   = (w >> 1) * 64;
    const int wn   = (w & 1) * 64;

    int bx, by;
    {
        int id  = blockIdx.x + gridDim.x * blockIdx.y;
        int xcd = id & 7;
        int j   = id >> 3;
        by = xcd * 4 + (j & 3);      // gy == 32
        bx = j >> 2;
    }
    const int m0 = by * 128;
    const int n0 = bx * 128;

    f32x4 acc[4][4];
    #pragma unroll
    for (int i = 0; i < 4; ++i)
        #pragma unroll
        for (int j = 0; j < 4; ++j)
            acc[i][j] = (f32x4){0.f, 0.f, 0.f, 0.f};

    const int srow = tid >> 2;
    const int sc8  = (tid & 3) * 8;
    const __bf16* gA0 = A  + (size_t)(m0 + srow) * K + sc8;
    const __bf16* gA1 = gA0 + (size_t)64 * K;
    const __bf16* gB0 = Bw + (size_t)(n0 + srow) * K + sc8;
    const __bf16* gB1 = gB0 + (size_t)64 * K;
    __bf16* lA0 = &As[srow * BK + sc8];
    __bf16* lA1 = &As[(srow + 64) * BK + sc8];
    __bf16* lB0 = &Bs[srow * BK + sc8];
    __bf16* lB1 = &Bs[(srow + 64) * BK + sc8];

    for (int k0 = 0; k0 < K; k0 += BK) {
        gld16(gA0 + k0, lA0);
        gld16(gA1 + k0, lA1);
        gld16(gB0 + k0, lB0);
        gld16(gB1 + k0, lB1);
        __syncthreads();

        bf16x8 af[4], bfr[4];
        #pragma unroll
        for (int i = 0; i < 4; ++i)
            af[i] = *(const bf16x8*)&As[(wm + i * 16 + lm) * BK + quad * 8];
        #pragma unroll
        for (int j = 0; j < 4; ++j)
            bfr[j] = *(const bf16x8*)&Bs[(wn + j * 16 + lm) * BK + quad * 8];
        #pragma unroll
        for (int i = 0; i < 4; ++i)
            #pragma unroll
            for (int j = 0; j < 4; ++j)
                acc[i][j] = mfma16(af[i], bfr[j], acc[i][j]);
        __syncthreads();
    }

    float sc = 1.0f;
    if (ROPE) {
        const int colbase = n0 + wn;            // 64-aligned; region-uniform per wave
        const int region  = (colbase < 2048) ? 0 : (colbase < 2560 ? 1 : 2);
        if (region < 2) {
            if (region == 0) sc = SCALE_Q;
            float invr[2];
            invr[0] = exp2f(-(float)lm        * L2IF) * INV2PI;
            invr[1] = exp2f(-(float)(16 + lm) * L2IF) * INV2PI;
            #pragma unroll
            for (int i = 0; i < 4; ++i)
                #pragma unroll
                for (int r = 0; r < 4; ++r) {
                    float t = (float)((m0 + wm + i * 16 + quad * 4 + r) & 2047);
                    #pragma unroll
                    for (int jp = 0; jp < 2; ++jp) {
                        float a = t * invr[jp];
                        a -= floorf(a);                       // revolutions in [0,1)
                        float cs = __builtin_amdgcn_cosf(a);
                        float sn = __builtin_amdgcn_sinf(a);
                        float x1 = acc[i][jp][r], x2 = acc[i][jp + 2][r];
                        acc[i][jp][r]     = x1 * cs - x2 * sn;
                        acc[i][jp + 2][r] = x2 * cs + x1 * sn;
                    }
                }
        }
    }

    #pragma unroll
    for (int i = 0; i < 4; ++i)
        #pragma unroll
        for (int j = 0; j < 4; ++j)
            #pragma unroll
            for (int r = 0; r < 4; ++r) {
                int row = m0 + wm + i * 16 + quad * 4 + r;
                int col = n0 + wn + j * 16 + lm;
                if (OUT_F32)
                    ((float*)Cv)[(size_t)row * N + col] = acc[i][j][r];
                else
                    ((__bf16*)Cv)[(size_t)row * N + col] = (__bf16)(acc[i][j][r] * sc);
            }
}

// ---------------- V transpose: [4096 tok][512 d] (stride 3072) -> [512][4096]
__global__ __launch_bounds__(256) void transpose_kernel(
    const __bf16* __restrict__ in, __bf16* __restrict__ out, int rowstride)
{
    __shared__ __bf16 T[64][72];
    const int t0 = blockIdx.x * 64;
    const int d0 = blockIdx.y * 64;
    const int r = threadIdx.x >> 2, c = (threadIdx.x & 3) * 16;
    *(int4*)&T[r][c]     = *(const int4*)(in + (size_t)(t0 + r) * rowstride + d0 + c);
    *(int4*)&T[r][c + 8] = *(const int4*)(in + (size_t)(t0 + r) * rowstride + d0 + c + 8);
    __syncthreads();
    bf16x8 o0, o1;
    #pragma unroll
    for (int i = 0; i < 8; ++i) { o0[i] = T[c + i][r]; o1[i] = T[c + 8 + i][r]; }
    *(bf16x8*)(out + (size_t)(d0 + r) * 4096 + t0 + c)     = o0;
    *(bf16x8*)(out + (size_t)(d0 + r) * 4096 + t0 + c + 8) = o1;
}

// ---------------- Flash attention (ROUND-4 exact) ---------------------------
// Transposed scores: St = mfma(A=K, B=Q) -> lane holds (kv=quad*4+r, q=lm).
// P packed to Pt[q][kv] with b64 writes; PV = mfma(A=Vt, B=Pt) -> O^T frags.
// Paired q-blocks (p, 15-p), K-tile 64, dbuf staging, 1 barrier/tile.
#define RS  72
#define PKS 72

__device__ inline void attn_tile(
    const bf16x8 (&qf)[2][2], f32x4 (&oacc)[2][4], float (&l)[2],
    int qbase, int k0, int w, int lm, int quad,
    const __bf16* Ks, const __bf16* Vs, __bf16* Ptw)
{
    f32x4 st[2][4];
    #pragma unroll
    for (int m = 0; m < 2; ++m)
        #pragma unroll
        for (int n = 0; n < 4; ++n)
            st[m][n] = (f32x4){0.f, 0.f, 0.f, 0.f};

    #pragma unroll
    for (int n = 0; n < 4; ++n) {
        bf16x8 kf0 = *(const bf16x8*)&Ks[(n * 16 + lm) * RS + quad * 8];
        bf16x8 kf1 = *(const bf16x8*)&Ks[(n * 16 + lm) * RS + 32 + quad * 8];
        #pragma unroll
        for (int m = 0; m < 2; ++m) {
            st[m][n] = mfma16(kf0, qf[m][0], st[m][n]);
            st[m][n] = mfma16(kf1, qf[m][1], st[m][n]);
        }
    }

    const bool any_mask = (k0 + 63 > qbase + w * 32);
    #pragma unroll
    for (int m = 0; m < 2; ++m) {
        const int qi = qbase + w * 32 + m * 16 + lm;
        #pragma unroll
        for (int n = 0; n < 4; ++n) {
            const int kv0 = k0 + n * 16 + quad * 4;
            float e0, e1, e2, e3;
            if (any_mask) {
                e0 = (kv0     > qi) ? 0.f : __expf(st[m][n][0]);
                e1 = (kv0 + 1 > qi) ? 0.f : __expf(st[m][n][1]);
                e2 = (kv0 + 2 > qi) ? 0.f : __expf(st[m][n][2]);
                e3 = (kv0 + 3 > qi) ? 0.f : __expf(st[m][n][3]);
            } else {
                e0 = __expf(st[m][n][0]); e1 = __expf(st[m][n][1]);
                e2 = __expf(st[m][n][2]); e3 = __expf(st[m][n][3]);
            }
            l[m] += (e0 + e1) + (e2 + e3);
            *(bf16x4*)&Ptw[(m * 16 + lm) * PKS + n * 16 + quad * 4] = pk4(e0, e1, e2, e3);
        }
    }

    bf16x8 pf[2][2];
    #pragma unroll
    for (int m = 0; m < 2; ++m) {
        pf[m][0] = *(const bf16x8*)&Ptw[(m * 16 + lm) * PKS + quad * 8];
        pf[m][1] = *(const bf16x8*)&Ptw[(m * 16 + lm) * PKS + 32 + quad * 8];
    }
    #pragma unroll
    for (int dt = 0; dt < 4; ++dt) {
        bf16x8 vf0 = *(const bf16x8*)&Vs[(dt * 16 + lm) * RS + quad * 8];
        bf16x8 vf1 = *(const bf16x8*)&Vs[(dt * 16 + lm) * RS + 32 + quad * 8];
        #pragma unroll
        for (int m = 0; m < 2; ++m) {
            oacc[m][dt] = mfma16(vf0, pf[m][0], oacc[m][dt]);
            oacc[m][dt] = mfma16(vf1, pf[m][1], oacc[m][dt]);
        }
    }
}

__device__ inline void attn_epilogue(
    f32x4 (&oacc)[2][4], float (&l)[2],
    int qbase, int w, int lm, int quad, int b, int h, __bf16* o)
{
    #pragma unroll
    for (int m = 0; m < 2; ++m) {
        float ls = l[m];
        ls += __shfl_xor(ls, 16);
        ls += __shfl_xor(ls, 32);
        float rinv = 1.0f / ls;
        const size_t rowbase = (size_t)(b * 2048 + qbase + w * 32 + m * 16 + lm) * 2048 + h * 64;
        #pragma unroll
        for (int dt = 0; dt < 4; ++dt) {
            *(bf16x4*)(o + rowbase + dt * 16 + quad * 4) =
                pk4(oacc[m][dt][0] * rinv, oacc[m][dt][1] * rinv,
                    oacc[m][dt][2] * rinv, oacc[m][dt][3] * rinv);
        }
    }
}

__global__ __launch_bounds__(256) void attn_kernel(
    const __bf16* __restrict__ qkv, const __bf16* __restrict__ vt,
    __bf16* __restrict__ o)
{
    __shared__ __bf16 Ks[2][64 * RS];
    __shared__ __bf16 Vs[2][64 * RS];
    __shared__ __bf16 Pt[4][32 * PKS];
    const int tid  = threadIdx.x;
    const int w    = tid >> 6;
    const int lane = tid & 63;
    const int lm   = lane & 15;
    const int quad = lane >> 4;
    const int p = blockIdx.x, h = blockIdx.y, b = blockIdx.z;
    const int kvh = h >> 2;
    const int qbA = p * 128, qbB = (15 - p) * 128;
    const int ntA = 2 * p + 2, ntB = 32 - 2 * p;
    __bf16* Ptw = &Pt[w][0];

    bf16x8 qfA[2][2], qfB[2][2];
    #pragma unroll
    for (int m = 0; m < 2; ++m)
        #pragma unroll
        for (int kh = 0; kh < 2; ++kh) {
            qfA[m][kh] = *(const bf16x8*)(qkv + (size_t)(b * 2048 + qbA + w * 32 + m * 16 + lm) * 3072
                                            + h * 64 + kh * 32 + quad * 8);
            qfB[m][kh] = *(const bf16x8*)(qkv + (size_t)(b * 2048 + qbB + w * 32 + m * 16 + lm) * 3072
                                            + h * 64 + kh * 32 + quad * 8);
        }

    f32x4 oA[2][4], oB[2][4];
    float lA[2] = {0.f, 0.f}, lB[2] = {0.f, 0.f};
    #pragma unroll
    for (int m = 0; m < 2; ++m)
        #pragma unroll
        for (int j = 0; j < 4; ++j) {
            oA[m][j] = (f32x4){0.f, 0.f, 0.f, 0.f};
            oB[m][j] = (f32x4){0.f, 0.f, 0.f, 0.f};
        }

    const int srow = tid >> 2;
    const int scol = (tid & 3) * 16;
    const __bf16* kbase = qkv + (size_t)(b * 2048) * 3072 + 2048 + kvh * 64;
    const __bf16* vbase = vt  + (size_t)(kvh * 64 + srow) * 4096 + b * 2048;

    int4 kr0, kr1, vr0, vr1;
    {
        const __bf16* kr = kbase + (size_t)srow * 3072 + scol;
        kr0 = *(const int4*)kr; kr1 = *(const int4*)(kr + 8);
        vr0 = *(const int4*)(vbase + scol); vr1 = *(const int4*)(vbase + scol + 8);
    }

    for (int kt = 0; kt < ntB; ++kt) {
        const int c = kt & 1;
        const int k0 = kt * 64;
        *(int4*)&Ks[c][srow * RS + scol]     = kr0;
        *(int4*)&Ks[c][srow * RS + scol + 8] = kr1;
        *(int4*)&Vs[c][srow * RS + scol]     = vr0;
        *(int4*)&Vs[c][srow * RS + scol + 8] = vr1;
        if (kt + 1 < ntB) {
            const __bf16* kr = kbase + (size_t)(k0 + 64 + srow) * 3072 + scol;
            kr0 = *(const int4*)kr; kr1 = *(const int4*)(kr + 8);
            vr0 = *(const int4*)(vbase + k0 + 64 + scol);
            vr1 = *(const int4*)(vbase + k0 + 64 + scol + 8);
        }
        __syncthreads();
        attn_tile(qfB, oB, lB, qbB, k0, w, lm, quad, Ks[c], Vs[c], Ptw);
        if (kt < ntA)
            attn_tile(qfA, oA, lA, qbA, k0, w, lm, quad, Ks[c], Vs[c], Ptw);
    }

    attn_epilogue(oA, lA, qbA, w, lm, quad, b, h, o);
    attn_epilogue(oB, lB, qbB, w, lm, quad, b, h, o);
}

// ---------------------------------------------------------------------------
extern "C" void kernel_launch(void* const* d_in, const int* in_sizes, int n_in,
                              void* d_out, int out_size, void* d_ws, size_t ws_size,
                              hipStream_t stream)
{
    const float* x  = (const float*)d_in[0];
    const float* Wq = (const float*)d_in[1];
    const float* Wk = (const float*)d_in[2];
    const float* Wv = (const float*)d_in[3];
    const float* Wo = (const float*)d_in[4];

    const size_t Mi = 1u << 20;
    // d_out (32 MiB fp32) is scratch until the final GEMM writes it.
    char* ob = (char*)d_out;
    __bf16* xb    = (__bf16*)ob;              // 16 MiB  [4096][2048]
    __bf16* wqkvb = (__bf16*)(ob + 16 * Mi);  // 12 MiB  [3072][2048]
    __bf16* vt    = (__bf16*)(ob + 28 * Mi);  //  4 MiB  [512][4096]
    // d_ws (>= 40 MiB, proven)
    char* ws = (char*)d_ws;
    __bf16* qkvc = (__bf16*)ws;               // 24 MiB  [4096][3072]  Q|K|V
    __bf16* aws  = (__bf16*)(ws + 24 * Mi);   // 16 MiB  [4096][2048]
    __bf16* wob  = (__bf16*)ws;               //  8 MiB, reuses qkvc after attn

    dim3 blk(256);
    cvt4_kernel<<<14336, blk, 0, stream>>>(x, Wq, Wk, Wv, xb, wqkvb);
    gemm_bt<true, false><<<dim3(24, 32), blk, 0, stream>>>(xb, wqkvb, qkvc, 4096, 3072, 2048);
    transpose_kernel<<<dim3(64, 8), blk, 0, stream>>>(qkvc + 2560, vt, 3072);
    attn_kernel<<<dim3(8, 32, 2), blk, 0, stream>>>(qkvc, vt, aws);
    cvt_kernel<<<4096, blk, 0, stream>>>(Wo, wob, 1048576);
    gemm_bt<false, true><<<dim3(16, 32), blk, 0, stream>>>(aws, wob, d_out, 4096, 2048, 2048);
}